// Round 9
// baseline (214.956 us; speedup 1.0000x reference)
//
#include <hip/hip_runtime.h>
#include <cstdint>
#include <cstddef>

constexpr int Bn = 64;     // batch
constexpr int Nn = 1024;   // nodes per graph
constexpr int Dn = 1024;   // input feature dim
constexpr int Cn = 128;    // hidden channels
constexpr int En = 16384;  // edges per graph

typedef short s16x8 __attribute__((ext_vector_type(8)));   // 8 bf16 = 4 VGPR (MFMA A/B frag)
typedef float f32x4 __attribute__((ext_vector_type(4)));   // MFMA C/D frag

__device__ __forceinline__ uint32_t f2bf(float f) {        // fp32 -> bf16 bits, RNE
    uint32_t u = __float_as_uint(f);
    return (u + 0x7fffu + ((u >> 16) & 1u)) >> 16;
}

// ================= K1: detect | Wc->bf16^T | embed partial dots =================
// blocks 0..63: int64-detect -> meta[1]; 64..127: wconv; 128..383: embedA.
// meta[1]==1 iff int32 edge data (ws poisoned 0xAA; all writers store 1 -> benign race).
__global__ __launch_bounds__(256) void k_prep(const int* __restrict__ ei32,
                                              const float* __restrict__ Wc,
                                              const float* __restrict__ x,
                                              const float* __restrict__ We,
                                              int* __restrict__ meta,
                                              unsigned short* __restrict__ Wt,
                                              float* __restrict__ pws) {
    int bid = blockIdx.x, tid = threadIdx.x;
    if (bid < 64) {
        __shared__ int sh;
        if (tid == 0) sh = 0;
        __syncthreads();
        int i = bid * 256 + tid;                 // [0, 16384)
        if (ei32[2 * i + 1]) atomicOr(&sh, 1);
        __syncthreads();
        if (tid == 0 && sh) meta[1] = 1;
    } else if (bid < 128) {
        int i = (bid - 64) * 256 + tid;          // [0, 16384)
        int n = i >> 7, k = i & 127;
        Wt[i] = (unsigned short)f2bf(Wc[k * Cn + n]);
    } else {
        __shared__ float sx[256];
        __shared__ float sp[256];
        int bq = bid - 128;
        int b = bq >> 2, q = bq & 3;
        int c = tid & 127, h2 = tid >> 7;
        sx[tid] = x[b * Dn + q * 256 + tid];
        __syncthreads();
        float acc = 0.f;
        int d0 = q * 256 + h2 * 128, dl = h2 * 128;
#pragma unroll 8
        for (int i = 0; i < 128; ++i) acc += sx[dl + i] * We[(d0 + i) * Cn + c];
        sp[h2 * 128 + c] = acc;
        __syncthreads();
        if (h2 == 0) pws[(b * 4 + q) * Cn + c] = sp[c] + sp[128 + c];
    }
}

// ================= K2: block 0 = whole graph chain (hist->scan->scatter+edeg->levels);
//                      blocks 1..64 = g[b] = relu(sum partials + be) @ Wc =================
__global__ __launch_bounds__(1024) void k_graph(const int* __restrict__ ei32,
                                                const float* __restrict__ pws,
                                                const float* __restrict__ be,
                                                const float* __restrict__ Wc,
                                                int* __restrict__ meta,
                                                int* __restrict__ offs,
                                                int* __restrict__ ssrc,
                                                float* __restrict__ edeg,
                                                int* __restrict__ L2,
                                                int* __restrict__ L3,
                                                float* __restrict__ g) {
    int bid = blockIdx.x, t = threadIdx.x;
    if (bid > 0) {
        if (t >= 128) return;
        __shared__ float se[Cn];
        int b = bid - 1, c = t;
        float e = pws[(b * 4 + 0) * Cn + c] + pws[(b * 4 + 1) * Cn + c] +
                  pws[(b * 4 + 2) * Cn + c] + pws[(b * 4 + 3) * Cn + c] + be[c];
        se[c] = fmaxf(e, 0.f);
        __syncthreads();
        float ga = 0.f;
#pragma unroll 8
        for (int k = 0; k < Cn; ++k) ga += se[k] * Wc[k * Cn + c];
        g[b * Cn + c] = ga;
        return;
    }
    __shared__ int sdeg[Nn];   // hist -> scan array -> reused as sf3
    __shared__ int sraw[Nn];   // raw degrees
    __shared__ int scur[Nn];   // scatter cursors -> reused as sf2
    __shared__ int soffs[Nn];  // exclusive offsets (stable copy)
    __shared__ int c3s, c2s;
    bool i64 = (meta[1] != 1);
    sdeg[t] = 0;
    if (t == 0) { c3s = 0; c2s = 0; }
    __syncthreads();
    // histogram of dst
    for (int e = t; e < En; e += 1024) {
        int dst = ei32[i64 ? 2 * (En + e) : (En + e)] & (Nn - 1);
        atomicAdd(&sdeg[dst], 1);
    }
    __syncthreads();
    int v = sdeg[t];
    sraw[t] = v;
    // inclusive scan in place
    for (int off = 1; off < Nn; off <<= 1) {
        int add = (t >= off) ? sdeg[t - off] : 0;
        __syncthreads();
        sdeg[t] += add;
        __syncthreads();
    }
    offs[t + 1] = sdeg[t];
    if (t == 0) offs[0] = 0;
    int ex = sdeg[t] - v;
    scur[t] = ex;
    soffs[t] = ex;
    __syncthreads();
    // scatter src by dst; fuse edeg[pos] = (float)indeg[src]
    for (int e = t; e < En; e += 1024) {
        int src = ei32[i64 ? 2 * e : e] & (Nn - 1);
        int dst = ei32[i64 ? 2 * (En + e) : (En + e)] & (Nn - 1);
        int pos = atomicAdd(&scur[dst], 1);
        if (pos >= 0 && pos < En) { ssrc[pos] = src; edeg[pos] = (float)sraw[src]; }
    }
    __syncthreads();
    // levels: F3 = in-neighbors(node0); F2 = in-neighbors(F3). Reuse sdeg/scur as flags.
    sdeg[t] = 0; scur[t] = 0;
    __syncthreads();
    int e1 = sraw[0];                           // edges into node 0 occupy ssrc[0, e1)
    for (int e = t; e < e1; e += 1024) sdeg[ssrc[e]] = 1;
    __syncthreads();
    if (sdeg[t]) {
        int lo = soffs[t], hi = lo + sraw[t];
        for (int e = lo; e < hi; ++e) scur[ssrc[e]] = 1;
    }
    __syncthreads();
    if (sdeg[t]) { int p = atomicAdd(&c3s, 1); L3[p] = t; }
    if (scur[t]) { int p = atomicAdd(&c2s, 1); L2[p] = t; }
    __syncthreads();
    if (t == 0) { meta[2] = c3s; meta[3] = c2s; }
}

constexpr int PAD = 136;     // LDS row stride in bf16 elems (16B-aligned: 272 B)

// ================= K3: whole per-sample conv pipeline, one block per sample =================
// phase A: conv1+2 over F2 tiles (conv1 analytic: relu(edeg*g+bc)); h2 -> global (same-block L1)
// phase B: conv3 over F3 tiles gathering h2;  h3 -> global
// phase C: conv4 on node 0 + classifier (fp32 exact)
__global__ __launch_bounds__(256) void k_fused(const float* __restrict__ g,
                                               const unsigned short* __restrict__ Wt,
                                               const float* __restrict__ Wc,
                                               const float* __restrict__ bc,
                                               const float* __restrict__ Wcls,
                                               const float* __restrict__ bcls,
                                               const int* __restrict__ offs,
                                               const int* __restrict__ ssrc,
                                               const float* __restrict__ edeg,
                                               const int* __restrict__ L2,
                                               const int* __restrict__ L3,
                                               const int* __restrict__ meta,
                                               float* __restrict__ h2f,
                                               float* __restrict__ h3f,
                                               float* __restrict__ out) {
    __shared__ unsigned short sSb[32 * PAD];   // 8.7 KB: MFMA A tile (bf16)
    __shared__ float sEd[32][64];              // 8 KB: staged edge degrees
    __shared__ int   sIdx[32][64];             // 8 KB: staged source indices
    __shared__ int snode[32], slo[32], scnt[32];
    __shared__ float sAgg[8][Cn];              // 4 KB
    __shared__ float sred[256];

    int b = blockIdx.x, tid = threadIdx.x;
    int w = tid >> 6, lane = tid & 63, m = lane & 15, quad = lane >> 4;
    int cnt2 = meta[3], cnt3 = meta[2];

    // B-fragments once, from global Wt (32 KB, L2-hot) -> 32 VGPRs for whole kernel
    s16x8 bf0[4], bf1[4];
#pragma unroll
    for (int ks = 0; ks < 4; ++ks) {
        int ko = ks * 32 + quad * 8;
        bf0[ks] = *(const s16x8*)&Wt[(w * 32 + m) * Cn + ko];
        bf1[ks] = *(const s16x8*)&Wt[(w * 32 + 16 + m) * Cn + ko];
    }

    int c2 = tid & 63;
    float gx = g[b * Cn + 2 * c2], gy = g[b * Cn + 2 * c2 + 1];
    float bx = bc[2 * c2], by = bc[2 * c2 + 1];

    // ---- phase A: conv1+2 over F2 ----
    for (int tile = 0; tile * 32 < cnt2; ++tile) {
        __syncthreads();
        if (tid < 32) {
            int ti = tile * 32 + tid;
            int node = (ti < cnt2) ? L2[ti] : -1;
            snode[tid] = node;
            int lo = (node >= 0) ? offs[node] : 0;
            int hi = (node >= 0) ? offs[node + 1] : 0;
            slo[tid] = lo; scnt[tid] = hi - lo;
        }
        __syncthreads();
#pragma unroll
        for (int r = 0; r < 8; ++r) {
            int row = w * 8 + r;
            int cnt = scnt[row];
            if (lane < cnt && lane < 64) sEd[row][lane] = edeg[slo[row] + lane];
        }
        __syncthreads();
#pragma unroll
        for (int t0 = 0; t0 < 8; ++t0) {
            int row = w * 8 + t0;
            int cnt = scnt[row], lo = slo[row];
            float s0 = 0.f, s1 = 0.f;
            int jm = cnt < 64 ? cnt : 64;
            for (int j = 0; j < jm; ++j) {
                float d = sEd[row][j];
                s0 += fmaxf(fmaf(d, gx, bx), 0.f);
                s1 += fmaxf(fmaf(d, gy, by), 0.f);
            }
            for (int j = 64; j < cnt; ++j) {          // rare overflow tail
                float d = edeg[lo + j];
                s0 += fmaxf(fmaf(d, gx, bx), 0.f);
                s1 += fmaxf(fmaf(d, gy, by), 0.f);
            }
            *(uint32_t*)&sSb[row * PAD + 2 * c2] = f2bf(s0) | (f2bf(s1) << 16);
        }
        __syncthreads();
        f32x4 acc[2][2];
#pragma unroll
        for (int rt = 0; rt < 2; ++rt)
#pragma unroll
            for (int ct = 0; ct < 2; ++ct) acc[rt][ct] = (f32x4){0.f, 0.f, 0.f, 0.f};
#pragma unroll
        for (int ks = 0; ks < 4; ++ks) {
            int ko = ks * 32 + quad * 8;
            s16x8 a0 = *(const s16x8*)&sSb[(0 * 16 + m) * PAD + ko];
            s16x8 a1 = *(const s16x8*)&sSb[(1 * 16 + m) * PAD + ko];
            acc[0][0] = __builtin_amdgcn_mfma_f32_16x16x32_bf16(a0, bf0[ks], acc[0][0], 0, 0, 0);
            acc[0][1] = __builtin_amdgcn_mfma_f32_16x16x32_bf16(a0, bf1[ks], acc[0][1], 0, 0, 0);
            acc[1][0] = __builtin_amdgcn_mfma_f32_16x16x32_bf16(a1, bf0[ks], acc[1][0], 0, 0, 0);
            acc[1][1] = __builtin_amdgcn_mfma_f32_16x16x32_bf16(a1, bf1[ks], acc[1][1], 0, 0, 0);
        }
#pragma unroll
        for (int rt = 0; rt < 2; ++rt)
#pragma unroll
            for (int ct = 0; ct < 2; ++ct) {
                int col = w * 32 + ct * 16 + m;
                float bias = bc[col];
#pragma unroll
                for (int reg = 0; reg < 4; ++reg) {
                    int row = rt * 16 + quad * 4 + reg;
                    int node = snode[row];
                    if (node >= 0)
                        h2f[((size_t)b * Nn + node) * Cn + col] = fmaxf(acc[rt][ct][reg] + bias, 0.f);
                }
            }
    }

    // ---- phase B: conv3 over F3 (gather h2, same-block L1-resident) ----
    for (int tile = 0; tile * 32 < cnt3; ++tile) {
        __syncthreads();
        if (tid < 32) {
            int ti = tile * 32 + tid;
            int node = (ti < cnt3) ? L3[ti] : -1;
            snode[tid] = node;
            int lo = (node >= 0) ? offs[node] : 0;
            int hi = (node >= 0) ? offs[node + 1] : 0;
            slo[tid] = lo; scnt[tid] = hi - lo;
        }
        __syncthreads();
#pragma unroll
        for (int r = 0; r < 8; ++r) {
            int row = w * 8 + r;
            int cnt = scnt[row];
            if (lane < cnt && lane < 64) sIdx[row][lane] = ssrc[slo[row] + lane];
        }
        __syncthreads();
        int c4 = tid & 31, u8 = tid >> 5;           // 4 ch/thread, rows u8*4..u8*4+3
        const float4* hb4 = (const float4*)(h2f + (size_t)b * (Nn * Cn));
#pragma unroll
        for (int t0 = 0; t0 < 4; ++t0) {
            int row = u8 * 4 + t0;
            int cnt = scnt[row], lo = slo[row];
            float4 a = {0.f, 0.f, 0.f, 0.f};
            int jm = cnt < 64 ? cnt : 64;
            for (int j = 0; j < jm; ++j) {
                float4 v = hb4[sIdx[row][j] * 32 + c4];
                a.x += v.x; a.y += v.y; a.z += v.z; a.w += v.w;
            }
            for (int j = 64; j < cnt; ++j) {         // rare overflow tail
                float4 v = hb4[ssrc[lo + j] * 32 + c4];
                a.x += v.x; a.y += v.y; a.z += v.z; a.w += v.w;
            }
            uint2 pk;
            pk.x = f2bf(a.x) | (f2bf(a.y) << 16);
            pk.y = f2bf(a.z) | (f2bf(a.w) << 16);
            *(uint2*)&sSb[row * PAD + c4 * 4] = pk;
        }
        __syncthreads();
        f32x4 acc[2][2];
#pragma unroll
        for (int rt = 0; rt < 2; ++rt)
#pragma unroll
            for (int ct = 0; ct < 2; ++ct) acc[rt][ct] = (f32x4){0.f, 0.f, 0.f, 0.f};
#pragma unroll
        for (int ks = 0; ks < 4; ++ks) {
            int ko = ks * 32 + quad * 8;
            s16x8 a0 = *(const s16x8*)&sSb[(0 * 16 + m) * PAD + ko];
            s16x8 a1 = *(const s16x8*)&sSb[(1 * 16 + m) * PAD + ko];
            acc[0][0] = __builtin_amdgcn_mfma_f32_16x16x32_bf16(a0, bf0[ks], acc[0][0], 0, 0, 0);
            acc[0][1] = __builtin_amdgcn_mfma_f32_16x16x32_bf16(a0, bf1[ks], acc[0][1], 0, 0, 0);
            acc[1][0] = __builtin_amdgcn_mfma_f32_16x16x32_bf16(a1, bf0[ks], acc[1][0], 0, 0, 0);
            acc[1][1] = __builtin_amdgcn_mfma_f32_16x16x32_bf16(a1, bf1[ks], acc[1][1], 0, 0, 0);
        }
#pragma unroll
        for (int rt = 0; rt < 2; ++rt)
#pragma unroll
            for (int ct = 0; ct < 2; ++ct) {
                int col = w * 32 + ct * 16 + m;
                float bias = bc[col];
#pragma unroll
                for (int reg = 0; reg < 4; ++reg) {
                    int row = rt * 16 + quad * 4 + reg;
                    int node = snode[row];
                    if (node >= 0)
                        h3f[((size_t)b * Nn + node) * Cn + col] = fmaxf(acc[rt][ct][reg] + bias, 0.f);
                }
            }
    }

    // ---- phase C: conv4 (node 0) + classifier, fp32 exact ----
    __syncthreads();
    int e1 = offs[1];
    int lim = e1 < 256 ? e1 : 256;
    int* sI = &sIdx[0][0];
    if (tid < lim) sI[tid] = ssrc[tid];
    __syncthreads();
    int c4 = tid & 31, u8 = tid >> 5;
    const float4* hb4 = (const float4*)(h3f + (size_t)b * (Nn * Cn));
    float4 a = {0.f, 0.f, 0.f, 0.f};
    for (int j = u8; j < lim; j += 8) {
        float4 v = hb4[sI[j] * 32 + c4];
        a.x += v.x; a.y += v.y; a.z += v.z; a.w += v.w;
    }
    for (int j = 256 + u8; j < e1; j += 8) {         // rare overflow tail
        float4 v = hb4[ssrc[j] * 32 + c4];
        a.x += v.x; a.y += v.y; a.z += v.z; a.w += v.w;
    }
    *(float4*)&sAgg[u8][c4 * 4] = a;
    __syncthreads();
    int c = tid & 127, half = tid >> 7;
    if (tid < 128) {
        float s = sAgg[0][c];
#pragma unroll
        for (int q = 1; q < 8; ++q) s += sAgg[q][c];
        sAgg[0][c] = s;
    }
    __syncthreads();
    float s = 0.f;
    int k0 = half * 64;
#pragma unroll 8
    for (int k = k0; k < k0 + 64; ++k) s += sAgg[0][k] * Wc[k * Cn + c];
    sred[tid] = s;
    __syncthreads();
    if (tid < 128) {
        float val = fmaxf(sred[c] + sred[128 + c] + bc[c], 0.f);
        sred[tid] = val * Wcls[c];
    }
    __syncthreads();
    for (int st = 64; st > 0; st >>= 1) {
        if (tid < st) sred[tid] += sred[tid + st];
        __syncthreads();
    }
    if (tid == 0) out[b] = sred[0] + bcls[0];
}

extern "C" void kernel_launch(void* const* d_in, const int* in_sizes, int n_in,
                              void* d_out, int out_size, void* d_ws, size_t ws_size,
                              hipStream_t stream) {
    const float* x    = (const float*)d_in[0];
    const int*   ei32 = (const int*)d_in[1];
    const float* We   = (const float*)d_in[2];
    const float* be   = (const float*)d_in[3];
    const float* Wc   = (const float*)d_in[4];
    const float* bc   = (const float*)d_in[5];
    const float* Wcls = (const float*)d_in[6];
    const float* bcls = (const float*)d_in[7];
    float* out = (float*)d_out;

    // ---- workspace layout ----
    // 0        g       32768    (B x C fp32)
    // 32768    meta     4096    (meta[1]=int32-detect; meta[2]=|F3|; meta[3]=|F2|)
    // 36864    offs     8192
    // 45056    ssrc    65536
    // 110592   edeg    65536    (fp32 degree per CSR-ordered edge)
    // 176128   L3       4096
    // 180224   L2       4096
    // 184320   Wt      32768    (128x128 bf16, transposed)
    // 217088   pws    131072    (embed partials)
    // 348160   h2f   33554432   (fp32, sparse-filled at F2 rows)
    // 33902592 h3f   33554432   (fp32, sparse-filled at F3 rows)
    char* ws = (char*)d_ws;
    float*          g    = (float*)(ws + 0);
    int*            meta = (int*)(ws + 32768);
    int*            offs = (int*)(ws + 36864);
    int*            ssrc = (int*)(ws + 45056);
    float*          edeg = (float*)(ws + 110592);
    int*            L3   = (int*)(ws + 176128);
    int*            L2   = (int*)(ws + 180224);
    unsigned short* Wt   = (unsigned short*)(ws + 184320);
    float*          pws  = (float*)(ws + 217088);
    float*          h2f  = (float*)(ws + 348160);
    float*          h3f  = (float*)(ws + 33902592);

    k_prep<<<384, 256, 0, stream>>>(ei32, Wc, x, We, meta, Wt, pws);
    k_graph<<<65, 1024, 0, stream>>>(ei32, pws, be, Wc, meta, offs, ssrc, edeg, L2, L3, g);
    k_fused<<<64, 256, 0, stream>>>(g, Wt, Wc, bc, Wcls, bcls, offs, ssrc, edeg,
                                    L2, L3, meta, h2f, h3f, out);
}

// Round 10
// 149.986 us; speedup vs baseline: 1.4332x; 1.4332x over previous
//
#include <hip/hip_runtime.h>
#include <cstdint>
#include <cstddef>

constexpr int Bn = 64;     // batch
constexpr int Nn = 1024;   // nodes per graph
constexpr int Dn = 1024;   // input feature dim
constexpr int Cn = 128;    // hidden channels
constexpr int En = 16384;  // edges per graph

typedef short s16x8 __attribute__((ext_vector_type(8)));   // 8 bf16 = 4 VGPR (MFMA A/B frag)
typedef float f32x4 __attribute__((ext_vector_type(4)));   // MFMA C/D frag

__device__ __forceinline__ uint32_t f2bf(float f) {        // fp32 -> bf16 bits, RNE
    uint32_t u = __float_as_uint(f);
    return (u + 0x7fffu + ((u >> 16) & 1u)) >> 16;
}

// ================= K1: detect | Wc->bf16^T | embed partial dots =================
// blocks 0..63: int64-detect -> meta[1]; 64..127: wconv; 128..383: embedA.
// meta[1]==1 iff int32 edge data (ws poisoned 0xAA; all writers store 1 -> benign race).
__global__ __launch_bounds__(256) void k_prep(const int* __restrict__ ei32,
                                              const float* __restrict__ Wc,
                                              const float* __restrict__ x,
                                              const float* __restrict__ We,
                                              int* __restrict__ meta,
                                              unsigned short* __restrict__ Wt,
                                              float* __restrict__ pws) {
    int bid = blockIdx.x, tid = threadIdx.x;
    if (bid < 64) {
        __shared__ int sh;
        if (tid == 0) sh = 0;
        __syncthreads();
        int i = bid * 256 + tid;                 // [0, 16384)
        if (ei32[2 * i + 1]) atomicOr(&sh, 1);
        __syncthreads();
        if (tid == 0 && sh) meta[1] = 1;
    } else if (bid < 128) {
        int i = (bid - 64) * 256 + tid;          // [0, 16384)
        int n = i >> 7, k = i & 127;
        Wt[i] = (unsigned short)f2bf(Wc[k * Cn + n]);
    } else {
        __shared__ float sx[256];
        __shared__ float sp[256];
        int bq = bid - 128;
        int b = bq >> 2, q = bq & 3;
        int c = tid & 127, h2 = tid >> 7;
        sx[tid] = x[b * Dn + q * 256 + tid];
        __syncthreads();
        float acc = 0.f;
        int d0 = q * 256 + h2 * 128, dl = h2 * 128;
#pragma unroll 8
        for (int i = 0; i < 128; ++i) acc += sx[dl + i] * We[(d0 + i) * Cn + c];
        sp[h2 * 128 + c] = acc;
        __syncthreads();
        if (h2 == 0) pws[(b * 4 + q) * Cn + c] = sp[c] + sp[128 + c];
    }
}

// ================= K2: block 0 = whole graph chain (hist->scan->scatter+edeg->levels);
//                      blocks 1..64 = g[b] = relu(sum partials + be) @ Wc =================
__global__ __launch_bounds__(1024) void k_graph(const int* __restrict__ ei32,
                                                const float* __restrict__ pws,
                                                const float* __restrict__ be,
                                                const float* __restrict__ Wc,
                                                int* __restrict__ meta,
                                                int* __restrict__ offs,
                                                int* __restrict__ ssrc,
                                                float* __restrict__ edeg,
                                                int* __restrict__ L2,
                                                int* __restrict__ L3,
                                                float* __restrict__ g) {
    int bid = blockIdx.x, t = threadIdx.x;
    if (bid > 0) {
        if (t >= 128) return;
        __shared__ float se[Cn];
        int b = bid - 1, c = t;
        float e = pws[(b * 4 + 0) * Cn + c] + pws[(b * 4 + 1) * Cn + c] +
                  pws[(b * 4 + 2) * Cn + c] + pws[(b * 4 + 3) * Cn + c] + be[c];
        se[c] = fmaxf(e, 0.f);
        __syncthreads();
        float ga = 0.f;
#pragma unroll 8
        for (int k = 0; k < Cn; ++k) ga += se[k] * Wc[k * Cn + c];
        g[b * Cn + c] = ga;
        return;
    }
    __shared__ int sdeg[Nn];   // hist -> scan array -> reused as sf3
    __shared__ int sraw[Nn];   // raw degrees
    __shared__ int scur[Nn];   // scatter cursors -> reused as sf2
    __shared__ int soffs[Nn];  // exclusive offsets (stable copy)
    __shared__ int c3s, c2s;
    bool i64 = (meta[1] != 1);
    sdeg[t] = 0;
    if (t == 0) { c3s = 0; c2s = 0; }
    __syncthreads();
    for (int e = t; e < En; e += 1024) {
        int dst = ei32[i64 ? 2 * (En + e) : (En + e)] & (Nn - 1);
        atomicAdd(&sdeg[dst], 1);
    }
    __syncthreads();
    int v = sdeg[t];
    sraw[t] = v;
    for (int off = 1; off < Nn; off <<= 1) {
        int add = (t >= off) ? sdeg[t - off] : 0;
        __syncthreads();
        sdeg[t] += add;
        __syncthreads();
    }
    offs[t + 1] = sdeg[t];
    if (t == 0) offs[0] = 0;
    int ex = sdeg[t] - v;
    scur[t] = ex;
    soffs[t] = ex;
    __syncthreads();
    // scatter src by dst; fuse edeg[pos] = (float)indeg[src]
    for (int e = t; e < En; e += 1024) {
        int src = ei32[i64 ? 2 * e : e] & (Nn - 1);
        int dst = ei32[i64 ? 2 * (En + e) : (En + e)] & (Nn - 1);
        int pos = atomicAdd(&scur[dst], 1);
        if (pos >= 0 && pos < En) { ssrc[pos] = src; edeg[pos] = (float)sraw[src]; }
    }
    __syncthreads();
    // levels: F3 = in-neighbors(node0); F2 = in-neighbors(F3). Reuse sdeg/scur as flags.
    sdeg[t] = 0; scur[t] = 0;
    __syncthreads();
    int e1 = sraw[0];                           // edges into node 0 occupy ssrc[0, e1)
    for (int e = t; e < e1; e += 1024) sdeg[ssrc[e]] = 1;
    __syncthreads();
    if (sdeg[t]) {
        int lo = soffs[t], hi = lo + sraw[t];
        for (int e = lo; e < hi; ++e) scur[ssrc[e]] = 1;
    }
    __syncthreads();
    if (sdeg[t]) { int p = atomicAdd(&c3s, 1); L3[p] = t; }
    if (scur[t]) { int p = atomicAdd(&c2s, 1); L2[p] = t; }
    __syncthreads();
    if (t == 0) { meta[2] = c3s; meta[3] = c2s; }
}

constexpr int PAD = 136;     // LDS row stride in bf16 elems

// ================= K3: conv 1+2 fused, frontier-restricted (tile-major: XCD = b%8) =================
__global__ __launch_bounds__(256, 4) void k_conv2L(const float* __restrict__ g,
                                                   float* __restrict__ h2,
                                                   const unsigned short* __restrict__ Wt,
                                                   const float* __restrict__ bc,
                                                   const int* __restrict__ offs,
                                                   const float* __restrict__ edeg,
                                                   const int* __restrict__ L2,
                                                   const int* __restrict__ meta) {
    int bidx = blockIdx.x;
    int tile = bidx >> 6, b = bidx & 63;
    int cnt2 = meta[3];
    if (tile * 32 >= cnt2) return;
    __shared__ unsigned short sSb[32 * PAD];  // 8.7 KB
    __shared__ float sEd[32][64];             // 8 KB
    __shared__ int snode[32], slo[32], scnt[32];
    int tid = threadIdx.x;
    if (tid < 32) {
        int ti = tile * 32 + tid;
        int node = (ti < cnt2) ? L2[ti] : -1;
        snode[tid] = node;
        int lo = (node >= 0) ? offs[node] : 0;
        int hi = (node >= 0) ? offs[node + 1] : 0;
        slo[tid] = lo; scnt[tid] = hi - lo;
    }
    __syncthreads();
    int w = tid >> 6, lane = tid & 63;
#pragma unroll
    for (int r = 0; r < 8; ++r) {
        int row = w * 8 + r;
        int cnt = scnt[row];
        if (lane < cnt && lane < 64) sEd[row][lane] = edeg[slo[row] + lane];
    }
    __syncthreads();

    int c2 = tid & 63;
    float gx = g[b * Cn + 2 * c2], gy = g[b * Cn + 2 * c2 + 1];
    float bx = bc[2 * c2], by = bc[2 * c2 + 1];
#pragma unroll
    for (int t0 = 0; t0 < 8; ++t0) {
        int row = w * 8 + t0;
        int cnt = scnt[row], lo = slo[row];
        float s0 = 0.f, s1 = 0.f;
        int jm = cnt < 64 ? cnt : 64;
        for (int j = 0; j < jm; ++j) {
            float d = sEd[row][j];
            s0 += fmaxf(fmaf(d, gx, bx), 0.f);
            s1 += fmaxf(fmaf(d, gy, by), 0.f);
        }
        for (int j = 64; j < cnt; ++j) {      // rare overflow tail
            float d = edeg[lo + j];
            s0 += fmaxf(fmaf(d, gx, bx), 0.f);
            s1 += fmaxf(fmaf(d, gy, by), 0.f);
        }
        *(uint32_t*)&sSb[row * PAD + 2 * c2] = f2bf(s0) | (f2bf(s1) << 16);
    }

    int m = lane & 15, quad = lane >> 4;
    s16x8 bf0[4], bf1[4];
#pragma unroll
    for (int ks = 0; ks < 4; ++ks) {
        int ko = ks * 32 + quad * 8;
        bf0[ks] = *(const s16x8*)&Wt[(w * 32 + m) * Cn + ko];
        bf1[ks] = *(const s16x8*)&Wt[(w * 32 + 16 + m) * Cn + ko];
    }
    __syncthreads();

    f32x4 acc[2][2];
#pragma unroll
    for (int rt = 0; rt < 2; ++rt)
#pragma unroll
        for (int ct = 0; ct < 2; ++ct) acc[rt][ct] = (f32x4){0.f, 0.f, 0.f, 0.f};
#pragma unroll
    for (int ks = 0; ks < 4; ++ks) {
        int ko = ks * 32 + quad * 8;
        s16x8 a0 = *(const s16x8*)&sSb[(0 * 16 + m) * PAD + ko];
        s16x8 a1 = *(const s16x8*)&sSb[(1 * 16 + m) * PAD + ko];
        acc[0][0] = __builtin_amdgcn_mfma_f32_16x16x32_bf16(a0, bf0[ks], acc[0][0], 0, 0, 0);
        acc[0][1] = __builtin_amdgcn_mfma_f32_16x16x32_bf16(a0, bf1[ks], acc[0][1], 0, 0, 0);
        acc[1][0] = __builtin_amdgcn_mfma_f32_16x16x32_bf16(a1, bf0[ks], acc[1][0], 0, 0, 0);
        acc[1][1] = __builtin_amdgcn_mfma_f32_16x16x32_bf16(a1, bf1[ks], acc[1][1], 0, 0, 0);
    }

#pragma unroll
    for (int rt = 0; rt < 2; ++rt)
#pragma unroll
        for (int ct = 0; ct < 2; ++ct) {
            int col = w * 32 + ct * 16 + m;
            float bias = bc[col];
#pragma unroll
            for (int reg = 0; reg < 4; ++reg) {
                int row = rt * 16 + quad * 4 + reg;
                int node = snode[row];
                if (node >= 0)
                    h2[((size_t)b * Nn + node) * Cn + col] = fmaxf(acc[rt][ct][reg] + bias, 0.f);
            }
        }
}

// ================= K4: conv 3, frontier-restricted (tile-major) =================
__global__ __launch_bounds__(256, 4) void k_conv3L(const float* __restrict__ h2,
                                                   float* __restrict__ h3,
                                                   const unsigned short* __restrict__ Wt,
                                                   const float* __restrict__ bc,
                                                   const int* __restrict__ offs,
                                                   const int* __restrict__ ssrc,
                                                   const int* __restrict__ L3,
                                                   const int* __restrict__ meta) {
    int bidx = blockIdx.x;
    int tile = bidx >> 6, b = bidx & 63;
    int cnt3 = meta[2];
    if (tile * 32 >= cnt3) return;
    __shared__ unsigned short sSb[32 * PAD];  // 8.7 KB
    __shared__ int sIdx[32][64];              // 8 KB
    __shared__ int snode[32], slo[32], scnt[32];
    int tid = threadIdx.x;
    if (tid < 32) {
        int ti = tile * 32 + tid;
        int node = (ti < cnt3) ? L3[ti] : -1;
        snode[tid] = node;
        int lo = (node >= 0) ? offs[node] : 0;
        int hi = (node >= 0) ? offs[node + 1] : 0;
        slo[tid] = lo; scnt[tid] = hi - lo;
    }
    __syncthreads();
    int w = tid >> 6, lane = tid & 63;
#pragma unroll
    for (int r = 0; r < 8; ++r) {
        int row = w * 8 + r;
        int cnt = scnt[row];
        if (lane < cnt && lane < 64) sIdx[row][lane] = ssrc[slo[row] + lane];
    }
    __syncthreads();

    int c4 = tid & 31, u = tid >> 5;          // 4 ch per thread, rows u*4..u*4+3
    const float4* hb4 = (const float4*)(h2 + (size_t)b * (Nn * Cn));
#pragma unroll
    for (int t0 = 0; t0 < 4; ++t0) {
        int row = u * 4 + t0;
        int cnt = scnt[row], lo = slo[row];
        float4 a = {0.f, 0.f, 0.f, 0.f};
        int jm = cnt < 64 ? cnt : 64;
        for (int j = 0; j < jm; ++j) {
            float4 v = hb4[sIdx[row][j] * 32 + c4];
            a.x += v.x; a.y += v.y; a.z += v.z; a.w += v.w;
        }
        for (int j = 64; j < cnt; ++j) {      // rare overflow tail
            float4 v = hb4[ssrc[lo + j] * 32 + c4];
            a.x += v.x; a.y += v.y; a.z += v.z; a.w += v.w;
        }
        uint2 pk;
        pk.x = f2bf(a.x) | (f2bf(a.y) << 16);
        pk.y = f2bf(a.z) | (f2bf(a.w) << 16);
        *(uint2*)&sSb[row * PAD + c4 * 4] = pk;
    }

    int m = lane & 15, quad = lane >> 4;
    s16x8 bf0[4], bf1[4];
#pragma unroll
    for (int ks = 0; ks < 4; ++ks) {
        int ko = ks * 32 + quad * 8;
        bf0[ks] = *(const s16x8*)&Wt[(w * 32 + m) * Cn + ko];
        bf1[ks] = *(const s16x8*)&Wt[(w * 32 + 16 + m) * Cn + ko];
    }
    __syncthreads();

    f32x4 acc[2][2];
#pragma unroll
    for (int rt = 0; rt < 2; ++rt)
#pragma unroll
        for (int ct = 0; ct < 2; ++ct) acc[rt][ct] = (f32x4){0.f, 0.f, 0.f, 0.f};
#pragma unroll
    for (int ks = 0; ks < 4; ++ks) {
        int ko = ks * 32 + quad * 8;
        s16x8 a0 = *(const s16x8*)&sSb[(0 * 16 + m) * PAD + ko];
        s16x8 a1 = *(const s16x8*)&sSb[(1 * 16 + m) * PAD + ko];
        acc[0][0] = __builtin_amdgcn_mfma_f32_16x16x32_bf16(a0, bf0[ks], acc[0][0], 0, 0, 0);
        acc[0][1] = __builtin_amdgcn_mfma_f32_16x16x32_bf16(a0, bf1[ks], acc[0][1], 0, 0, 0);
        acc[1][0] = __builtin_amdgcn_mfma_f32_16x16x32_bf16(a1, bf0[ks], acc[1][0], 0, 0, 0);
        acc[1][1] = __builtin_amdgcn_mfma_f32_16x16x32_bf16(a1, bf1[ks], acc[1][1], 0, 0, 0);
    }

#pragma unroll
    for (int rt = 0; rt < 2; ++rt)
#pragma unroll
        for (int ct = 0; ct < 2; ++ct) {
            int col = w * 32 + ct * 16 + m;
            float bias = bc[col];
#pragma unroll
            for (int reg = 0; reg < 4; ++reg) {
                int row = rt * 16 + quad * 4 + reg;
                int node = snode[row];
                if (node >= 0)
                    h3[((size_t)b * Nn + node) * Cn + col] = fmaxf(acc[rt][ct][reg] + bias, 0.f);
            }
        }
}

// ================= K5: conv 4 (node 0 only) + classifier, fp32 exact =================
__global__ __launch_bounds__(256) void k_conv4cls(const float* __restrict__ h3,
                                                  const float* __restrict__ Wc,
                                                  const float* __restrict__ bc,
                                                  const float* __restrict__ Wcls,
                                                  const float* __restrict__ bcls,
                                                  const int* __restrict__ offs,
                                                  const int* __restrict__ ssrc,
                                                  float* __restrict__ out) {
    __shared__ float sAgg[8][Cn];   // 4 KB
    __shared__ float sred[256];
    __shared__ int sI[256];
    int b = blockIdx.x, tid = threadIdx.x;
    int e1 = offs[1];
    int lim = e1 < 256 ? e1 : 256;
    if (tid < lim) sI[tid] = ssrc[tid];
    __syncthreads();
    int c4 = tid & 31, u = tid >> 5;
    const float4* hb4 = (const float4*)(h3 + (size_t)b * (Nn * Cn));
    float4 a = {0.f, 0.f, 0.f, 0.f};
    for (int j = u; j < lim; j += 8) {
        float4 v = hb4[sI[j] * 32 + c4];
        a.x += v.x; a.y += v.y; a.z += v.z; a.w += v.w;
    }
    for (int j = 256 + u; j < e1; j += 8) {   // rare overflow tail
        float4 v = hb4[ssrc[j] * 32 + c4];
        a.x += v.x; a.y += v.y; a.z += v.z; a.w += v.w;
    }
    *(float4*)&sAgg[u][c4 * 4] = a;
    __syncthreads();
    int c = tid & 127, half = tid >> 7;
    if (tid < 128) {
        float s = sAgg[0][c];
#pragma unroll
        for (int q = 1; q < 8; ++q) s += sAgg[q][c];
        sAgg[0][c] = s;
    }
    __syncthreads();
    float s = 0.f;
    int k0 = half * 64;
#pragma unroll 8
    for (int k = k0; k < k0 + 64; ++k) s += sAgg[0][k] * Wc[k * Cn + c];
    sred[tid] = s;
    __syncthreads();
    if (tid < 128) {
        float val = fmaxf(sred[c] + sred[128 + c] + bc[c], 0.f);
        sred[tid] = val * Wcls[c];
    }
    __syncthreads();
    for (int st = 64; st > 0; st >>= 1) {
        if (tid < st) sred[tid] += sred[tid + st];
        __syncthreads();
    }
    if (tid == 0) out[b] = sred[0] + bcls[0];
}

extern "C" void kernel_launch(void* const* d_in, const int* in_sizes, int n_in,
                              void* d_out, int out_size, void* d_ws, size_t ws_size,
                              hipStream_t stream) {
    const float* x    = (const float*)d_in[0];
    const int*   ei32 = (const int*)d_in[1];
    const float* We   = (const float*)d_in[2];
    const float* be   = (const float*)d_in[3];
    const float* Wc   = (const float*)d_in[4];
    const float* bc   = (const float*)d_in[5];
    const float* Wcls = (const float*)d_in[6];
    const float* bcls = (const float*)d_in[7];
    float* out = (float*)d_out;

    // ---- workspace layout ----
    // 0        g       32768    (B x C fp32)
    // 32768    meta     4096    (meta[1]=int32-detect; meta[2]=|F3|; meta[3]=|F2|)
    // 36864    offs     8192
    // 45056    ssrc    65536
    // 110592   edeg    65536    (fp32 degree per CSR-ordered edge)
    // 176128   L3       4096
    // 180224   L2       4096
    // 184320   Wt      32768    (128x128 bf16, transposed)
    // 217088   pws    131072    (embed partials)
    // 348160   h2f   33554432   (fp32, sparse-filled at F2 rows)
    // 33902592 h3f   33554432   (fp32, sparse-filled at F3 rows)
    char* ws = (char*)d_ws;
    float*          g    = (float*)(ws + 0);
    int*            meta = (int*)(ws + 32768);
    int*            offs = (int*)(ws + 36864);
    int*            ssrc = (int*)(ws + 45056);
    float*          edeg = (float*)(ws + 110592);
    int*            L3   = (int*)(ws + 176128);
    int*            L2   = (int*)(ws + 180224);
    unsigned short* Wt   = (unsigned short*)(ws + 184320);
    float*          pws  = (float*)(ws + 217088);
    float*          h2f  = (float*)(ws + 348160);
    float*          h3f  = (float*)(ws + 33902592);

    k_prep<<<384, 256, 0, stream>>>(ei32, Wc, x, We, meta, Wt, pws);
    k_graph<<<65, 1024, 0, stream>>>(ei32, pws, be, Wc, meta, offs, ssrc, edeg, L2, L3, g);
    k_conv2L<<<32 * Bn, 256, 0, stream>>>(g, h2f, Wt, bc, offs, edeg, L2, meta);
    k_conv3L<<<32 * Bn, 256, 0, stream>>>(h2f, h3f, Wt, bc, offs, ssrc, L3, meta);
    k_conv4cls<<<Bn, 256, 0, stream>>>(h3f, Wc, bc, Wcls, bcls, offs, ssrc, out);
}